// Round 1
// baseline (5454.970 us; speedup 1.0000x reference)
//
#include <hip/hip_runtime.h>

// LSTM_RNN: B=8192, T=2048, H=51, 2-layer LSTM + linear head.
// Strategy: batch-parallel blocks (16 rows/block), sequential t-loop in-kernel.
// Wave w of each block owns gate section w (i,f,g,o). Weights as MFMA B-frags
// in registers. h kept as bf16 hi+lo pair (fp32-accurate recurrence), c in
// fp32 registers. Gate exchange + h exchange via LDS.

#define B_TOT 8192
#define T_LEN 2048
#define MR    16          // batch rows per block
#define ROWW  152         // u16 cols per h row: [hi 0..50][0 51..63][lo 64..114][0 ...]
#define GSTR  56          // float stride of gate-exchange rows
#define GSEC  (MR*GSTR)   // floats per gate section = 896

typedef __bf16 bf16x8 __attribute__((ext_vector_type(8)));
typedef float  f32x4  __attribute__((ext_vector_type(4)));

static __device__ __forceinline__ unsigned short f2us_bf(float f) {
    unsigned int u; __builtin_memcpy(&u, &f, 4);
    u = (u + 0x7FFFu + ((u >> 16) & 1u)) >> 16;   // RNE
    return (unsigned short)u;
}
static __device__ __forceinline__ float us2f(unsigned short u) {
    unsigned int w = ((unsigned int)u) << 16;
    float f; __builtin_memcpy(&f, &w, 4);
    return f;
}
static __device__ __forceinline__ __bf16 us2bf(unsigned short u) {
    __bf16 b; __builtin_memcpy(&b, &u, 2);
    return b;
}
// scalar weight load -> bf16 bits, handles f32 or bf16 globals
static __device__ __forceinline__ unsigned short ldw(const void* p, int idx, bool isbf) {
    return isbf ? ((const unsigned short*)p)[idx]
                : f2us_bf(((const float*)p)[idx]);
}
// scalar load -> f32, handles f32 or bf16 globals
static __device__ __forceinline__ float ldf(const void* p, int idx, bool isbf) {
    return isbf ? us2f(((const unsigned short*)p)[idx])
                : ((const float*)p)[idx];
}
// sigma(v) (kk=-log2e,aa=1,bb=0) or tanh(v) (kk=-2log2e,aa=2,bb=-1)
static __device__ __forceinline__ float sig_like(float v, float kk, float aa, float bb) {
    float e = __builtin_amdgcn_exp2f(kk * v);
    float r = __builtin_amdgcn_rcpf(1.0f + e);
    return fmaf(aa, r, bb);
}
static __device__ __forceinline__ float tanh_fast(float v) {
    float e = __builtin_amdgcn_exp2f(-2.8853900817779268f * v);
    float r = __builtin_amdgcn_rcpf(1.0f + e);
    return fmaf(2.0f, r, -1.0f);
}

__global__ __launch_bounds__(256, 2)
void lstm2_kernel(const void* __restrict__ xin,
                  const void* __restrict__ Wih1, const void* __restrict__ Whh1,
                  const void* __restrict__ bih1, const void* __restrict__ bhh1,
                  const void* __restrict__ Wih2, const void* __restrict__ Whh2,
                  const void* __restrict__ bih2, const void* __restrict__ bhh2,
                  const void* __restrict__ Wlin, const void* __restrict__ blin,
                  void* __restrict__ outp)
{
    const int tid  = threadIdx.x;
    const int wv   = tid >> 6;     // wave id == gate section (i,f,g,o)
    const int ln   = tid & 63;
    const int lid  = ln & 15;      // MFMA n / m index
    const int quad = ln >> 4;
    const int b0   = blockIdx.x * MR;

    __shared__ alignas(16) unsigned short hx1[MR * ROWW];  // h1 hi|lo (bf16 bits)
    __shared__ alignas(16) unsigned short h2b[MR * ROWW];  // h2 hi|lo
    __shared__ alignas(16) float Gbuf[4 * GSEC];           // activated gates, 4 sections
    __shared__ alignas(16) float xs[MR];                   // staged x_t (fp32)

    // ---- dtype sniff: are the globals bf16 or f32? (wave-uniform) ----
    // f32 buffer: even u16 halves are mantissa garbage -> implausible bf16 exponents.
    bool isbf;
    {
        const unsigned short* xu = (const unsigned short*)xin;
        int cnt = 0;
        #pragma unroll
        for (int i = 0; i < 64; i += 2) {
            unsigned e = (xu[i] >> 7) & 0xFFu;
            cnt += (e >= 115u && e <= 131u) ? 1 : 0;  // |v| in ~[2^-12, 32]
        }
        isbf = (cnt >= 16);
    }

    // ---- weight B-fragments in registers (loaded once) ----
    // B-frag lane layout: B[k = quad*8+j (+32*kb)][n = 16*nt + lid]
    bf16x8 B1[4][2], B2i[4][2], B2h[4][2];
    float bias1[4], bias2[4], wih1v[4];
    {
        const int secbase = 51 * wv;
        #pragma unroll
        for (int n = 0; n < 4; ++n) {
            const int rowloc = 16*n + lid;         // col within padded section
            const int g = secbase + rowloc;        // global gate row
            const bool rv = (rowloc < 51);
            #pragma unroll
            for (int kb = 0; kb < 2; ++kb) {
                bf16x8 f1, f2i, f2h;
                #pragma unroll
                for (int j = 0; j < 8; ++j) {
                    const int k = kb*32 + quad*8 + j;
                    unsigned short v1 = 0, v2i = 0, v2h = 0;
                    if (rv && k < 51) {
                        v1  = ldw(Whh1, g*51 + k, isbf);
                        v2i = ldw(Wih2, g*51 + k, isbf);
                        v2h = ldw(Whh2, g*51 + k, isbf);
                    } else if (!rv && wv == 3 && rowloc == 51 && k < 51) {
                        v2h = ldw(Wlin, k, isbf);  // free y-column in o-section
                    }
                    f1[j] = us2bf(v1); f2i[j] = us2bf(v2i); f2h[j] = us2bf(v2h);
                }
                B1[n][kb] = f1; B2i[n][kb] = f2i; B2h[n][kb] = f2h;
            }
            bias1[n] = rv ? (ldf(bih1, g, isbf) + ldf(bhh1, g, isbf)) : 0.0f;
            bias2[n] = rv ? (ldf(bih2, g, isbf) + ldf(bhh2, g, isbf))
                          : ((wv == 3 && rowloc == 51) ? ldf(blin, 0, isbf) : 0.0f);
            wih1v[n] = rv ? ldf(Wih1, g, isbf) : 0.0f;   // x * W_ih1 folded into acc init
        }
    }

    // ---- per-thread (b,j) update assignment: e = tid + 256*s, e < 16*51 ----
    int gaf[4] = {0,0,0,0};
    int haf[4] = {0,0,0,0};
    #pragma unroll
    for (int s = 0; s < 4; ++s) {
        const int e = tid + 256*s;
        if (e < MR*51) {
            const int b = e / 51;
            const int j = e - 51*b;
            gaf[s] = b*GSTR + j;
            haf[s] = b*ROWW + j;
        }
    }
    float c1[4] = {0,0,0,0}, c2[4] = {0,0,0,0};

    // activation constants (wave-uniform; wave 2 = tanh for g-gate)
    const float kk = (wv == 2) ? -2.8853900817779268f : -1.4426950408889634f;
    const float aa = (wv == 2) ?  2.0f : 1.0f;
    const float bb = (wv == 2) ? -1.0f : 0.0f;

    // ---- init LDS: zero h buffers (incl. permanent zero pads), stage x[.,0] ----
    for (int i = tid; i < MR*ROWW; i += 256) { hx1[i] = 0; h2b[i] = 0; }
    if (tid < MR) xs[tid] = ldf(xin, (b0 + tid)*T_LEN, isbf);
    __syncthreads();

    #pragma unroll 1
    for (int t = 0; t < T_LEN; ++t) {
        // ========== P1: layer-1 gates for this wave's section ==========
        const f32x4  xv = *(const f32x4*)&xs[quad*4];
        const bf16x8 a0 = *(const bf16x8*)&hx1[lid*ROWW +      quad*8];
        const bf16x8 a1 = *(const bf16x8*)&hx1[lid*ROWW + 32 + quad*8];
        const bf16x8 a2 = *(const bf16x8*)&hx1[lid*ROWW + 64 + quad*8];  // lo part
        const bf16x8 a3 = *(const bf16x8*)&hx1[lid*ROWW + 96 + quad*8];
        #pragma unroll
        for (int n = 0; n < 4; ++n) {
            f32x4 acc;
            acc[0] = fmaf(xv[0], wih1v[n], bias1[n]);
            acc[1] = fmaf(xv[1], wih1v[n], bias1[n]);
            acc[2] = fmaf(xv[2], wih1v[n], bias1[n]);
            acc[3] = fmaf(xv[3], wih1v[n], bias1[n]);
            acc = __builtin_amdgcn_mfma_f32_16x16x32_bf16(a0, B1[n][0], acc, 0,0,0);
            acc = __builtin_amdgcn_mfma_f32_16x16x32_bf16(a1, B1[n][1], acc, 0,0,0);
            acc = __builtin_amdgcn_mfma_f32_16x16x32_bf16(a2, B1[n][0], acc, 0,0,0);
            acc = __builtin_amdgcn_mfma_f32_16x16x32_bf16(a3, B1[n][1], acc, 0,0,0);
            const int coln = 16*n + lid;
            const float g0 = sig_like(acc[0], kk, aa, bb);
            const float g1 = sig_like(acc[1], kk, aa, bb);
            const float g2 = sig_like(acc[2], kk, aa, bb);
            const float g3 = sig_like(acc[3], kk, aa, bb);
            if (coln < 51) {
                float* gp = &Gbuf[wv*GSEC + (quad*4)*GSTR + coln];
                gp[0] = g0; gp[GSTR] = g1; gp[2*GSTR] = g2; gp[3*GSTR] = g3;
            }
        }
        __syncthreads();

        // ========== P2: layer-1 cell/hidden update (+ prefetch x[t+1]) ==========
        #pragma unroll
        for (int s = 0; s < 4; ++s) {
            if (s < 3 || tid < 48) {
                const int ga = gaf[s];
                const float I  = Gbuf[ga];
                const float F  = Gbuf[ga +   GSEC];
                const float Gg = Gbuf[ga + 2*GSEC];
                const float O  = Gbuf[ga + 3*GSEC];
                const float c  = fmaf(F, c1[s], I * Gg);
                c1[s] = c;
                const float h = O * tanh_fast(c);
                const unsigned short hi = f2us_bf(h);
                const unsigned short lo = f2us_bf(h - us2f(hi));
                hx1[haf[s]]      = hi;
                hx1[haf[s] + 64] = lo;
            }
        }
        if (tid < MR) {
            xs[tid] = (t + 1 < T_LEN) ? ldf(xin, (b0 + tid)*T_LEN + t + 1, isbf) : 0.0f;
        }
        __syncthreads();

        // ========== P3: layer-2 gates (+ extract y[t-1] from padding col) ==========
        const bf16x8 p0 = *(const bf16x8*)&hx1[lid*ROWW +      quad*8];
        const bf16x8 p1 = *(const bf16x8*)&hx1[lid*ROWW + 32 + quad*8];
        const bf16x8 p2 = *(const bf16x8*)&hx1[lid*ROWW + 64 + quad*8];
        const bf16x8 p3 = *(const bf16x8*)&hx1[lid*ROWW + 96 + quad*8];
        const bf16x8 q0 = *(const bf16x8*)&h2b[lid*ROWW +      quad*8];
        const bf16x8 q1 = *(const bf16x8*)&h2b[lid*ROWW + 32 + quad*8];
        const bf16x8 q2 = *(const bf16x8*)&h2b[lid*ROWW + 64 + quad*8];
        const bf16x8 q3 = *(const bf16x8*)&h2b[lid*ROWW + 96 + quad*8];
        #pragma unroll
        for (int n = 0; n < 4; ++n) {
            f32x4 acc = {bias2[n], bias2[n], bias2[n], bias2[n]};
            acc = __builtin_amdgcn_mfma_f32_16x16x32_bf16(p0, B2i[n][0], acc, 0,0,0);
            acc = __builtin_amdgcn_mfma_f32_16x16x32_bf16(p1, B2i[n][1], acc, 0,0,0);
            acc = __builtin_amdgcn_mfma_f32_16x16x32_bf16(p2, B2i[n][0], acc, 0,0,0);
            acc = __builtin_amdgcn_mfma_f32_16x16x32_bf16(p3, B2i[n][1], acc, 0,0,0);
            acc = __builtin_amdgcn_mfma_f32_16x16x32_bf16(q0, B2h[n][0], acc, 0,0,0);
            acc = __builtin_amdgcn_mfma_f32_16x16x32_bf16(q1, B2h[n][1], acc, 0,0,0);
            acc = __builtin_amdgcn_mfma_f32_16x16x32_bf16(q2, B2h[n][0], acc, 0,0,0);
            acc = __builtin_amdgcn_mfma_f32_16x16x32_bf16(q3, B2h[n][1], acc, 0,0,0);
            if (n == 3 && wv == 3 && lid == 3 && t > 0) {
                // col 51 of o-section == b_lin + W_lin . h2_prev == y[t-1]
                #pragma unroll
                for (int r = 0; r < 4; ++r) {
                    const int idx = (b0 + quad*4 + r)*T_LEN + (t - 1);
                    if (isbf) ((unsigned short*)outp)[idx] = f2us_bf(acc[r]);
                    else      ((float*)outp)[idx] = acc[r];
                }
            }
            const int coln = 16*n + lid;
            const float g0 = sig_like(acc[0], kk, aa, bb);
            const float g1 = sig_like(acc[1], kk, aa, bb);
            const float g2 = sig_like(acc[2], kk, aa, bb);
            const float g3 = sig_like(acc[3], kk, aa, bb);
            if (coln < 51) {
                float* gp = &Gbuf[wv*GSEC + (quad*4)*GSTR + coln];
                gp[0] = g0; gp[GSTR] = g1; gp[2*GSTR] = g2; gp[3*GSTR] = g3;
            }
        }
        __syncthreads();

        // ========== P4: layer-2 cell/hidden update ==========
        #pragma unroll
        for (int s = 0; s < 4; ++s) {
            if (s < 3 || tid < 48) {
                const int ga = gaf[s];
                const float I  = Gbuf[ga];
                const float F  = Gbuf[ga +   GSEC];
                const float Gg = Gbuf[ga + 2*GSEC];
                const float O  = Gbuf[ga + 3*GSEC];
                const float c  = fmaf(F, c2[s], I * Gg);
                c2[s] = c;
                const float h = O * tanh_fast(c);
                const unsigned short hi = f2us_bf(h);
                const unsigned short lo = f2us_bf(h - us2f(hi));
                h2b[haf[s]]      = hi;
                h2b[haf[s] + 64] = lo;
            }
        }
        __syncthreads();
    }

    // ---- flush y[T-1] from final h2 ----
    if (wv == 3) {
        const bf16x8 q0 = *(const bf16x8*)&h2b[lid*ROWW +      quad*8];
        const bf16x8 q1 = *(const bf16x8*)&h2b[lid*ROWW + 32 + quad*8];
        const bf16x8 q2 = *(const bf16x8*)&h2b[lid*ROWW + 64 + quad*8];
        const bf16x8 q3 = *(const bf16x8*)&h2b[lid*ROWW + 96 + quad*8];
        f32x4 acc = {bias2[3], bias2[3], bias2[3], bias2[3]};
        acc = __builtin_amdgcn_mfma_f32_16x16x32_bf16(q0, B2h[3][0], acc, 0,0,0);
        acc = __builtin_amdgcn_mfma_f32_16x16x32_bf16(q1, B2h[3][1], acc, 0,0,0);
        acc = __builtin_amdgcn_mfma_f32_16x16x32_bf16(q2, B2h[3][0], acc, 0,0,0);
        acc = __builtin_amdgcn_mfma_f32_16x16x32_bf16(q3, B2h[3][1], acc, 0,0,0);
        if (lid == 3) {
            #pragma unroll
            for (int r = 0; r < 4; ++r) {
                const int idx = (b0 + quad*4 + r)*T_LEN + (T_LEN - 1);
                if (isbf) ((unsigned short*)outp)[idx] = f2us_bf(acc[r]);
                else      ((float*)outp)[idx] = acc[r];
            }
        }
    }
}

extern "C" void kernel_launch(void* const* d_in, const int* in_sizes, int n_in,
                              void* d_out, int out_size, void* d_ws, size_t ws_size,
                              hipStream_t stream) {
    (void)in_sizes; (void)n_in; (void)out_size; (void)d_ws; (void)ws_size;
    dim3 grid(B_TOT / MR), block(256);
    lstm2_kernel<<<grid, block, 0, stream>>>(
        d_in[0], d_in[1], d_in[2], d_in[3], d_in[4], d_in[5],
        d_in[6], d_in[7], d_in[8], d_in[9], d_in[10], d_out);
}

// Round 2
// 4154.178 us; speedup vs baseline: 1.3131x; 1.3131x over previous
//
#include <hip/hip_runtime.h>

// LSTM_RNN: B=8192, T=2048, H=51, 2-layer LSTM + linear head.
// R2 restructure: each wave owns j-slice [13w,13w+13) of H and computes ALL
// four gate types (4 MFMA N-tiles = i,f,g,o). MFMA C-layout puts I,F,G,O for
// one (b,j) in the same lane -> cell update is pure in-register, no gate
// exchange through LDS. h1/h2 state ping-pong in LDS (bf16 hi+lo pair for
// fp32-accurate recurrence); 2 barriers/step (was 4). y = W_lin.h2 rides in
// a free pad column (wave3, lid12, o-tile) of the layer-2 MFMA.

#define B_TOT 8192
#define T_LEN 2048
#define MR    16          // batch rows per block
#define ROWW  152         // u16 cols per h row: [hi 0..50][0][lo 64..114][0]
#define HB    (MR*ROWW)   // u16 per h buffer (2432)

typedef __bf16 bf16x8 __attribute__((ext_vector_type(8)));
typedef float  f32x4  __attribute__((ext_vector_type(4)));

static __device__ __forceinline__ unsigned short f2us_bf(float f) {
    unsigned int u; __builtin_memcpy(&u, &f, 4);
    u = (u + 0x7FFFu + ((u >> 16) & 1u)) >> 16;   // RNE
    return (unsigned short)u;
}
static __device__ __forceinline__ float us2f(unsigned short u) {
    unsigned int w = ((unsigned int)u) << 16;
    float f; __builtin_memcpy(&f, &w, 4);
    return f;
}
static __device__ __forceinline__ __bf16 us2bf(unsigned short u) {
    __bf16 b; __builtin_memcpy(&b, &u, 2);
    return b;
}
static __device__ __forceinline__ unsigned short ldw(const void* p, int idx, bool isbf) {
    return isbf ? ((const unsigned short*)p)[idx]
                : f2us_bf(((const float*)p)[idx]);
}
static __device__ __forceinline__ float ldf(const void* p, int idx, bool isbf) {
    return isbf ? us2f(((const unsigned short*)p)[idx])
                : ((const float*)p)[idx];
}
static __device__ __forceinline__ float sigmoid_fast(float v) {
    float e = __builtin_amdgcn_exp2f(-1.4426950408889634f * v);
    float r = __builtin_amdgcn_rcpf(1.0f + e);
    return r;
}
static __device__ __forceinline__ float tanh_fast(float v) {
    float e = __builtin_amdgcn_exp2f(-2.8853900817779268f * v);
    float r = __builtin_amdgcn_rcpf(1.0f + e);
    return fmaf(2.0f, r, -1.0f);
}
static __device__ __forceinline__ f32x4 act4(f32x4 v, bool isg) {
    f32x4 o;
    #pragma unroll
    for (int r = 0; r < 4; ++r) o[r] = isg ? tanh_fast(v[r]) : sigmoid_fast(v[r]);
    return o;
}

__global__ __launch_bounds__(256, 2)
void lstm2_kernel(const void* __restrict__ xin,
                  const void* __restrict__ Wih1, const void* __restrict__ Whh1,
                  const void* __restrict__ bih1, const void* __restrict__ bhh1,
                  const void* __restrict__ Wih2, const void* __restrict__ Whh2,
                  const void* __restrict__ bih2, const void* __restrict__ bhh2,
                  const void* __restrict__ Wlin, const void* __restrict__ blin,
                  void* __restrict__ outp)
{
    const int tid  = threadIdx.x;
    const int wv   = tid >> 6;     // wave id -> j-slice [13w, 13w+13)
    const int ln   = tid & 63;
    const int lid  = ln & 15;      // MFMA col within tile
    const int quad = ln >> 4;
    const int b0   = blockIdx.x * MR;
    const int jcol = 13*wv + lid;
    const bool valid = (lid < 13) && (jcol < 51);
    const bool ylane = (wv == 3) && (lid == 12);   // free pad col -> y head

    __shared__ alignas(16) unsigned short hx[2*HB];  // h1 ping-pong (hi|lo bf16)
    __shared__ alignas(16) unsigned short h2[2*HB];  // h2 ping-pong
    __shared__ alignas(16) float xs[MR];

    // ---- dtype sniff (f32 vs bf16 globals), wave-uniform ----
    bool isbf;
    {
        const unsigned short* xu = (const unsigned short*)xin;
        int cnt = 0;
        #pragma unroll
        for (int i = 0; i < 64; i += 2) {
            unsigned e = (xu[i] >> 7) & 0xFFu;
            cnt += (e >= 115u && e <= 131u) ? 1 : 0;
        }
        isbf = (cnt >= 16);
    }

    // ---- weight B-fragments in registers ----
    // tile n = gate type (0:i 1:f 2:g 3:o); col lid -> j = 13w+lid; row g = 51n+j
    // B-frag element j8 at k = kb*32 + quad*8 + j8
    bf16x8 B1[4][2], B2i[4][2], B2h[4][2];
    float bias1[4], bias2[4], wih1v[4];
    {
        #pragma unroll
        for (int n = 0; n < 4; ++n) {
            const int g = 51*n + jcol;
            #pragma unroll
            for (int kb = 0; kb < 2; ++kb) {
                bf16x8 f1, f2i, f2h;
                #pragma unroll
                for (int j8 = 0; j8 < 8; ++j8) {
                    const int k = kb*32 + quad*8 + j8;
                    unsigned short v1 = 0, v2i = 0, v2h = 0;
                    if (valid && k < 51) {
                        v1  = ldw(Whh1, g*51 + k, isbf);
                        v2i = ldw(Wih2, g*51 + k, isbf);
                        v2h = ldw(Whh2, g*51 + k, isbf);
                    } else if (ylane && n == 3 && k < 51) {
                        v2h = ldw(Wlin, k, isbf);
                    }
                    f1[j8] = us2bf(v1); f2i[j8] = us2bf(v2i); f2h[j8] = us2bf(v2h);
                }
                B1[n][kb] = f1; B2i[n][kb] = f2i; B2h[n][kb] = f2h;
            }
            bias1[n] = valid ? (ldf(bih1, g, isbf) + ldf(bhh1, g, isbf)) : 0.0f;
            bias2[n] = valid ? (ldf(bih2, g, isbf) + ldf(bhh2, g, isbf))
                             : ((ylane && n == 3) ? ldf(blin, 0, isbf) : 0.0f);
            wih1v[n] = valid ? ldf(Wih1, g, isbf) : 0.0f;
        }
    }

    float c1[4] = {0,0,0,0}, c2[4] = {0,0,0,0};

    // ---- init LDS: zero both parities of both h buffers, stage x[.,0] ----
    for (int i = tid; i < 2*HB; i += 256) { hx[i] = 0; h2[i] = 0; }
    if (tid < MR) xs[tid] = ldf(xin, (b0 + tid)*T_LEN, isbf);
    __syncthreads();

    int pr = HB, pw = 0;   // read-parity / write-parity offsets

    #pragma unroll 1
    for (int t = 0; t < T_LEN; ++t) {
        // ===== P1: layer-1 gates + in-register cell update =====
        const f32x4  xv = *(const f32x4*)&xs[quad*4];
        const int    ra = pr + lid*ROWW + quad*8;
        const bf16x8 a0 = *(const bf16x8*)&hx[ra];
        const bf16x8 a1 = *(const bf16x8*)&hx[ra + 32];
        const bf16x8 a2 = *(const bf16x8*)&hx[ra + 64];   // lo part
        const bf16x8 a3 = *(const bf16x8*)&hx[ra + 96];
        f32x4 act[4];
        #pragma unroll
        for (int n = 0; n < 4; ++n) {
            f32x4 acc;
            #pragma unroll
            for (int r = 0; r < 4; ++r) acc[r] = fmaf(xv[r], wih1v[n], bias1[n]);
            acc = __builtin_amdgcn_mfma_f32_16x16x32_bf16(a0, B1[n][0], acc, 0,0,0);
            acc = __builtin_amdgcn_mfma_f32_16x16x32_bf16(a1, B1[n][1], acc, 0,0,0);
            acc = __builtin_amdgcn_mfma_f32_16x16x32_bf16(a2, B1[n][0], acc, 0,0,0);
            acc = __builtin_amdgcn_mfma_f32_16x16x32_bf16(a3, B1[n][1], acc, 0,0,0);
            act[n] = act4(acc, n == 2);
        }
        #pragma unroll
        for (int r = 0; r < 4; ++r) {
            const float c = fmaf(act[1][r], c1[r], act[0][r] * act[2][r]);
            c1[r] = c;
            const float h = act[3][r] * tanh_fast(c);
            const unsigned short hi = f2us_bf(h);
            const unsigned short lo = f2us_bf(h - us2f(hi));
            if (valid) {
                const int wa = pw + (quad*4 + r)*ROWW + jcol;
                hx[wa]      = hi;
                hx[wa + 64] = lo;
            }
        }
        __syncthreads();

        // ===== P2: layer-2 gates (+ y from pad col) + in-register update =====
        const int    rp = pw + lid*ROWW + quad*8;   // h1(t) just written
        const int    rq = pr + lid*ROWW + quad*8;   // h2(t-1)
        const bf16x8 p0 = *(const bf16x8*)&hx[rp];
        const bf16x8 p1 = *(const bf16x8*)&hx[rp + 32];
        const bf16x8 p2 = *(const bf16x8*)&hx[rp + 64];
        const bf16x8 p3 = *(const bf16x8*)&hx[rp + 96];
        const bf16x8 q0 = *(const bf16x8*)&h2[rq];
        const bf16x8 q1 = *(const bf16x8*)&h2[rq + 32];
        const bf16x8 q2 = *(const bf16x8*)&h2[rq + 64];
        const bf16x8 q3 = *(const bf16x8*)&h2[rq + 96];
        #pragma unroll
        for (int n = 0; n < 4; ++n) {
            f32x4 acc = {bias2[n], bias2[n], bias2[n], bias2[n]};
            acc = __builtin_amdgcn_mfma_f32_16x16x32_bf16(p0, B2i[n][0], acc, 0,0,0);
            acc = __builtin_amdgcn_mfma_f32_16x16x32_bf16(p1, B2i[n][1], acc, 0,0,0);
            acc = __builtin_amdgcn_mfma_f32_16x16x32_bf16(p2, B2i[n][0], acc, 0,0,0);
            acc = __builtin_amdgcn_mfma_f32_16x16x32_bf16(p3, B2i[n][1], acc, 0,0,0);
            acc = __builtin_amdgcn_mfma_f32_16x16x32_bf16(q0, B2h[n][0], acc, 0,0,0);
            acc = __builtin_amdgcn_mfma_f32_16x16x32_bf16(q1, B2h[n][1], acc, 0,0,0);
            acc = __builtin_amdgcn_mfma_f32_16x16x32_bf16(q2, B2h[n][0], acc, 0,0,0);
            acc = __builtin_amdgcn_mfma_f32_16x16x32_bf16(q3, B2h[n][1], acc, 0,0,0);
            if (n == 3 && ylane && t > 0) {
                // pad col 51 of o-tile: blin + W_lin . h2(t-1) == y[t-1]
                #pragma unroll
                for (int r = 0; r < 4; ++r) {
                    const int idx = (b0 + quad*4 + r)*T_LEN + (t - 1);
                    if (isbf) ((unsigned short*)outp)[idx] = f2us_bf(acc[r]);
                    else      ((float*)outp)[idx] = acc[r];
                }
            }
            act[n] = act4(acc, n == 2);
        }
        #pragma unroll
        for (int r = 0; r < 4; ++r) {
            const float c = fmaf(act[1][r], c2[r], act[0][r] * act[2][r]);
            c2[r] = c;
            const float h = act[3][r] * tanh_fast(c);
            const unsigned short hi = f2us_bf(h);
            const unsigned short lo = f2us_bf(h - us2f(hi));
            if (valid) {
                const int wa = pw + (quad*4 + r)*ROWW + jcol;
                h2[wa]      = hi;
                h2[wa + 64] = lo;
            }
        }
        if (tid < MR) {
            xs[tid] = (t + 1 < T_LEN) ? ldf(xin, (b0 + tid)*T_LEN + t + 1, isbf) : 0.0f;
        }
        __syncthreads();
        const int tmp = pr; pr = pw; pw = tmp;
    }

    // ---- flush y[T-1] from final h2 (at offset pr after last swap) ----
    if (wv == 3) {
        const int    rq = pr + lid*ROWW + quad*8;
        const bf16x8 q0 = *(const bf16x8*)&h2[rq];
        const bf16x8 q1 = *(const bf16x8*)&h2[rq + 32];
        const bf16x8 q2 = *(const bf16x8*)&h2[rq + 64];
        const bf16x8 q3 = *(const bf16x8*)&h2[rq + 96];
        f32x4 acc = {bias2[3], bias2[3], bias2[3], bias2[3]};
        acc = __builtin_amdgcn_mfma_f32_16x16x32_bf16(q0, B2h[3][0], acc, 0,0,0);
        acc = __builtin_amdgcn_mfma_f32_16x16x32_bf16(q1, B2h[3][1], acc, 0,0,0);
        acc = __builtin_amdgcn_mfma_f32_16x16x32_bf16(q2, B2h[3][0], acc, 0,0,0);
        acc = __builtin_amdgcn_mfma_f32_16x16x32_bf16(q3, B2h[3][1], acc, 0,0,0);
        if (lid == 12) {
            #pragma unroll
            for (int r = 0; r < 4; ++r) {
                const int idx = (b0 + quad*4 + r)*T_LEN + (T_LEN - 1);
                if (isbf) ((unsigned short*)outp)[idx] = f2us_bf(acc[r]);
                else      ((float*)outp)[idx] = acc[r];
            }
        }
    }
}

extern "C" void kernel_launch(void* const* d_in, const int* in_sizes, int n_in,
                              void* d_out, int out_size, void* d_ws, size_t ws_size,
                              hipStream_t stream) {
    (void)in_sizes; (void)n_in; (void)out_size; (void)d_ws; (void)ws_size;
    dim3 grid(B_TOT / MR), block(256);
    lstm2_kernel<<<grid, block, 0, stream>>>(
        d_in[0], d_in[1], d_in[2], d_in[3], d_in[4], d_in[5],
        d_in[6], d_in[7], d_in[8], d_in[9], d_in[10], d_out);
}

// Round 3
// 3423.169 us; speedup vs baseline: 1.5935x; 1.2135x over previous
//
#include <hip/hip_runtime.h>

// LSTM_RNN: B=8192, T=2048, H=51, 2-layer LSTM + linear head.
// R3: producer-consumer layer pipeline. Block = 512 thr = 8 waves, MR=16
// batch rows. Waves 0-3 run layer 1 for all t; waves 4-7 run layer 2 one
// step behind (h1 handed through LDS ping-pong). 1 barrier per iteration.
// Each wave owns j-slice [13w,13w+13) and all 4 gate tiles; cell update is
// in-register (MFMA C-layout puts I,F,G,O of one (b,j) in one lane).
// h kept as bf16 hi+lo pair (fp32-accurate recurrence), c fp32 in regs.
// Gate scale -log2e (-2log2e for g) pre-folded into weights/biases.
// y = W_lin.h2 rides in pad column (wave7, lid12) of the layer-2 MFMA.

#define B_TOT 8192
#define T_LEN 2048
#define MR    16
#define ROWW  152         // bf16 cols per h row: [hi 0..50][0][lo 64..114][0]
#define HB    (MR*ROWW)   // elems per h parity buffer

typedef __bf16 bf16x8 __attribute__((ext_vector_type(8)));
typedef float  f32x4  __attribute__((ext_vector_type(4)));

#define LOG2E  1.4426950408889634f

static __device__ __forceinline__ float us2f(unsigned short u) {
    unsigned int w = ((unsigned int)u) << 16;
    float f; __builtin_memcpy(&f, &w, 4);
    return f;
}
// load f32 from f32 or bf16 global
static __device__ __forceinline__ float ldf(const void* p, int idx, bool isbf) {
    return isbf ? us2f(((const unsigned short*)p)[idx])
                : ((const float*)p)[idx];
}
static __device__ __forceinline__ float tanh_fast(float v) {
    float e = __builtin_amdgcn_exp2f(-2.0f * LOG2E * v);
    float r = __builtin_amdgcn_rcpf(1.0f + e);
    return fmaf(2.0f, r, -1.0f);
}
// pre-activation already scaled by -log2e (or -2log2e for g)
static __device__ __forceinline__ f32x4 act4s(f32x4 v, bool isg) {
    f32x4 o;
    #pragma unroll
    for (int r = 0; r < 4; ++r) {
        float e = __builtin_amdgcn_exp2f(v[r]);
        float rc = __builtin_amdgcn_rcpf(1.0f + e);
        o[r] = isg ? fmaf(2.0f, rc, -1.0f) : rc;
    }
    return o;
}
static __device__ __forceinline__ void store_y(void* outp, bool isbf, int idx, float v) {
    if (isbf) {
        __bf16 ob = (__bf16)v;
        unsigned short u; __builtin_memcpy(&u, &ob, 2);
        ((unsigned short*)outp)[idx] = u;
    } else {
        ((float*)outp)[idx] = v;
    }
}

__global__ __launch_bounds__(512, 4)
void lstm2_kernel(const void* __restrict__ xin,
                  const void* __restrict__ Wih1, const void* __restrict__ Whh1,
                  const void* __restrict__ bih1, const void* __restrict__ bhh1,
                  const void* __restrict__ Wih2, const void* __restrict__ Whh2,
                  const void* __restrict__ bih2, const void* __restrict__ bhh2,
                  const void* __restrict__ Wlin, const void* __restrict__ blin,
                  void* __restrict__ outp)
{
    const int tid  = threadIdx.x;
    const int wset = tid >> 8;         // 0: layer-1 waves, 1: layer-2 waves
    const int wv   = (tid >> 6) & 3;   // j-slice within set
    const int ln   = tid & 63;
    const int lid  = ln & 15;
    const int quad = ln >> 4;
    const int b0   = blockIdx.x * MR;
    const int jcol = 13*wv + lid;
    const bool valid = (lid < 13) && (jcol < 51);
    const bool ylane = (wv == 3) && (lid == 12);   // pad col 51 -> y head

    __shared__ __bf16 hx[2*HB];    // h1 ping-pong (hi|lo planes)
    __shared__ __bf16 h2b[2*HB];   // h2 ping-pong
    __shared__ float  xs[2][MR];   // x_t double buffer

    // ---- dtype sniff (f32 vs bf16 globals), block-uniform ----
    bool isbf;
    {
        const unsigned short* xu = (const unsigned short*)xin;
        int cnt = 0;
        #pragma unroll
        for (int i = 0; i < 64; i += 2) {
            unsigned e = (xu[i] >> 7) & 0xFFu;
            cnt += (e >= 115u && e <= 131u) ? 1 : 0;
        }
        isbf = (cnt >= 16);
    }

    // ---- init LDS ----
    for (int i = tid; i < 2*HB; i += 512) {
        hx[i]  = (__bf16)0.0f;
        h2b[i] = (__bf16)0.0f;
    }
    if (tid < MR) xs[0][tid] = ldf(xin, (b0 + tid)*T_LEN, isbf);
    __syncthreads();

    if (wset == 0) {
        // ================= LAYER-1 WAVES =================
        // B-frag: B[k = kb*32 + quad*8 + j8][n-col = lid], scaled by sn
        bf16x8 B1[4][2];
        float  bias1[4], wih1v[4];
        #pragma unroll
        for (int n = 0; n < 4; ++n) {
            const int g = 51*n + jcol;
            const float sn = (n == 2) ? -2.0f*LOG2E : -LOG2E;
            #pragma unroll
            for (int kb = 0; kb < 2; ++kb) {
                bf16x8 f;
                #pragma unroll
                for (int j8 = 0; j8 < 8; ++j8) {
                    const int k = kb*32 + quad*8 + j8;
                    float v = 0.0f;
                    if (valid && k < 51) v = sn * ldf(Whh1, g*51 + k, isbf);
                    f[j8] = (__bf16)v;
                }
                B1[n][kb] = f;
            }
            bias1[n] = valid ? sn * (ldf(bih1, g, isbf) + ldf(bhh1, g, isbf)) : 0.0f;
            wih1v[n] = valid ? sn * ldf(Wih1, g, isbf) : 0.0f;
        }
        float c1[4] = {0,0,0,0};

        #pragma unroll 2
        for (int k = 0; k <= T_LEN; ++k) {
            if (k < T_LEN) {
                const int rs = (k - 1) & 1, ws = k & 1;
                const f32x4 xv = *(const f32x4*)&xs[k & 1][quad*4];
                const __bf16* hp = &hx[rs*HB + lid*ROWW + quad*8];
                f32x4 acc[4];
                #pragma unroll
                for (int n = 0; n < 4; ++n)
                    #pragma unroll
                    for (int r = 0; r < 4; ++r)
                        acc[n][r] = fmaf(xv[r], wih1v[n], bias1[n]);
                bf16x8 a;
                a = *(const bf16x8*)(hp);
                #pragma unroll
                for (int n = 0; n < 4; ++n) acc[n] = __builtin_amdgcn_mfma_f32_16x16x32_bf16(a, B1[n][0], acc[n], 0,0,0);
                a = *(const bf16x8*)(hp + 32);
                #pragma unroll
                for (int n = 0; n < 4; ++n) acc[n] = __builtin_amdgcn_mfma_f32_16x16x32_bf16(a, B1[n][1], acc[n], 0,0,0);
                a = *(const bf16x8*)(hp + 64);   // lo plane
                #pragma unroll
                for (int n = 0; n < 4; ++n) acc[n] = __builtin_amdgcn_mfma_f32_16x16x32_bf16(a, B1[n][0], acc[n], 0,0,0);
                a = *(const bf16x8*)(hp + 96);
                #pragma unroll
                for (int n = 0; n < 4; ++n) acc[n] = __builtin_amdgcn_mfma_f32_16x16x32_bf16(a, B1[n][1], acc[n], 0,0,0);

                f32x4 act[4];
                #pragma unroll
                for (int n = 0; n < 4; ++n) act[n] = act4s(acc[n], n == 2);
                #pragma unroll
                for (int r = 0; r < 4; ++r) {
                    const float c = fmaf(act[1][r], c1[r], act[0][r] * act[2][r]);
                    c1[r] = c;
                    const float h = act[3][r] * tanh_fast(c);
                    const __bf16 hb = (__bf16)h;
                    const __bf16 lb = (__bf16)(h - (float)hb);
                    if (valid) {
                        const int wa = ws*HB + (quad*4 + r)*ROWW + jcol;
                        hx[wa]      = hb;
                        hx[wa + 64] = lb;
                    }
                }
                if (tid < MR)
                    xs[(k+1) & 1][tid] = (k+1 < T_LEN) ? ldf(xin, (b0 + tid)*T_LEN + k + 1, isbf) : 0.0f;
            }
            __syncthreads();
        }
    } else {
        // ================= LAYER-2 WAVES =================
        bf16x8 B2i[4][2], B2h[4][2];
        float  bias2[4];
        #pragma unroll
        for (int n = 0; n < 4; ++n) {
            const int g = 51*n + jcol;
            const float sn = (n == 2) ? -2.0f*LOG2E : -LOG2E;
            #pragma unroll
            for (int kb = 0; kb < 2; ++kb) {
                bf16x8 fi, fh;
                #pragma unroll
                for (int j8 = 0; j8 < 8; ++j8) {
                    const int k = kb*32 + quad*8 + j8;
                    float vi = 0.0f, vh = 0.0f;
                    if (valid && k < 51) {
                        vi = sn * ldf(Wih2, g*51 + k, isbf);
                        vh = sn * ldf(Whh2, g*51 + k, isbf);
                    } else if (ylane && n == 3 && k < 51) {
                        vh = ldf(Wlin, k, isbf);   // unscaled y head
                    }
                    fi[j8] = (__bf16)vi; fh[j8] = (__bf16)vh;
                }
                B2i[n][kb] = fi; B2h[n][kb] = fh;
            }
            bias2[n] = valid ? sn * (ldf(bih2, g, isbf) + ldf(bhh2, g, isbf))
                             : ((ylane && n == 3) ? ldf(blin, 0, isbf) : 0.0f);
        }
        float c2[4] = {0,0,0,0};

        #pragma unroll 2
        for (int k = 0; k <= T_LEN; ++k) {
            if (k >= 1) {
                const int rs1 = (k - 1) & 1;   // h1(k-1)
                const int rs2 = k & 1;         // h2(k-2)
                const int ws2 = (k - 1) & 1;   // h2(k-1)
                const __bf16* h1p = &hx [rs1*HB + lid*ROWW + quad*8];
                const __bf16* h2p = &h2b[rs2*HB + lid*ROWW + quad*8];
                f32x4 acc[4];
                #pragma unroll
                for (int n = 0; n < 4; ++n) acc[n] = (f32x4){bias2[n], bias2[n], bias2[n], bias2[n]};
                bf16x8 a;
                a = *(const bf16x8*)(h1p);
                #pragma unroll
                for (int n = 0; n < 4; ++n) acc[n] = __builtin_amdgcn_mfma_f32_16x16x32_bf16(a, B2i[n][0], acc[n], 0,0,0);
                a = *(const bf16x8*)(h1p + 32);
                #pragma unroll
                for (int n = 0; n < 4; ++n) acc[n] = __builtin_amdgcn_mfma_f32_16x16x32_bf16(a, B2i[n][1], acc[n], 0,0,0);
                a = *(const bf16x8*)(h1p + 64);
                #pragma unroll
                for (int n = 0; n < 4; ++n) acc[n] = __builtin_amdgcn_mfma_f32_16x16x32_bf16(a, B2i[n][0], acc[n], 0,0,0);
                a = *(const bf16x8*)(h1p + 96);
                #pragma unroll
                for (int n = 0; n < 4; ++n) acc[n] = __builtin_amdgcn_mfma_f32_16x16x32_bf16(a, B2i[n][1], acc[n], 0,0,0);
                a = *(const bf16x8*)(h2p);
                #pragma unroll
                for (int n = 0; n < 4; ++n) acc[n] = __builtin_amdgcn_mfma_f32_16x16x32_bf16(a, B2h[n][0], acc[n], 0,0,0);
                a = *(const bf16x8*)(h2p + 32);
                #pragma unroll
                for (int n = 0; n < 4; ++n) acc[n] = __builtin_amdgcn_mfma_f32_16x16x32_bf16(a, B2h[n][1], acc[n], 0,0,0);
                a = *(const bf16x8*)(h2p + 64);
                #pragma unroll
                for (int n = 0; n < 4; ++n) acc[n] = __builtin_amdgcn_mfma_f32_16x16x32_bf16(a, B2h[n][0], acc[n], 0,0,0);
                a = *(const bf16x8*)(h2p + 96);
                #pragma unroll
                for (int n = 0; n < 4; ++n) acc[n] = __builtin_amdgcn_mfma_f32_16x16x32_bf16(a, B2h[n][1], acc[n], 0,0,0);

                // pad col 51 of o-tile: blin + Wlin . h2(k-2) == y[k-2]
                if (ylane && k >= 2) {
                    #pragma unroll
                    for (int r = 0; r < 4; ++r)
                        store_y(outp, isbf, (b0 + quad*4 + r)*T_LEN + (k - 2), acc[3][r]);
                }

                f32x4 act[4];
                #pragma unroll
                for (int n = 0; n < 4; ++n) act[n] = act4s(acc[n], n == 2);
                #pragma unroll
                for (int r = 0; r < 4; ++r) {
                    const float c = fmaf(act[1][r], c2[r], act[0][r] * act[2][r]);
                    c2[r] = c;
                    const float h = act[3][r] * tanh_fast(c);
                    const __bf16 hb = (__bf16)h;
                    const __bf16 lb = (__bf16)(h - (float)hb);
                    if (valid) {
                        const int wa = ws2*HB + (quad*4 + r)*ROWW + jcol;
                        h2b[wa]      = hb;
                        h2b[wa + 64] = lb;
                    }
                }
            }
            __syncthreads();
        }

        // ---- flush y[T-1] from final h2 (slot (T-1)&1) ----
        if (wv == 3) {
            const __bf16* h2p = &h2b[((T_LEN - 1) & 1)*HB + lid*ROWW + quad*8];
            f32x4 acc = {bias2[3], bias2[3], bias2[3], bias2[3]};
            bf16x8 a;
            a = *(const bf16x8*)(h2p);
            acc = __builtin_amdgcn_mfma_f32_16x16x32_bf16(a, B2h[3][0], acc, 0,0,0);
            a = *(const bf16x8*)(h2p + 32);
            acc = __builtin_amdgcn_mfma_f32_16x16x32_bf16(a, B2h[3][1], acc, 0,0,0);
            a = *(const bf16x8*)(h2p + 64);
            acc = __builtin_amdgcn_mfma_f32_16x16x32_bf16(a, B2h[3][0], acc, 0,0,0);
            a = *(const bf16x8*)(h2p + 96);
            acc = __builtin_amdgcn_mfma_f32_16x16x32_bf16(a, B2h[3][1], acc, 0,0,0);
            if (lid == 12) {
                #pragma unroll
                for (int r = 0; r < 4; ++r)
                    store_y(outp, isbf, (b0 + quad*4 + r)*T_LEN + (T_LEN - 1), acc[r]);
            }
        }
    }
}

extern "C" void kernel_launch(void* const* d_in, const int* in_sizes, int n_in,
                              void* d_out, int out_size, void* d_ws, size_t ws_size,
                              hipStream_t stream) {
    (void)in_sizes; (void)n_in; (void)out_size; (void)d_ws; (void)ws_size;
    dim3 grid(B_TOT / MR), block(512);
    lstm2_kernel<<<grid, block, 0, stream>>>(
        d_in[0], d_in[1], d_in[2], d_in[3], d_in[4], d_in[5],
        d_in[6], d_in[7], d_in[8], d_in[9], d_in[10], d_out);
}

// Round 4
// 2628.190 us; speedup vs baseline: 2.0756x; 1.3025x over previous
//
#include <hip/hip_runtime.h>

// LSTM_RNN: B=8192, T=2048, H=51, 2-layer LSTM + linear head.
// R4: fp16 MFMA path (no hi/lo split; fp16 mantissa 11b beats bf16 hi-only),
// x and bias folded into K-slots 51/52 of the A-matrix (B rows carry
// W_ih1/bias pre-scaled by -log2e), paired-rcp activations (one v_rcp per
// two sigmoids), LDS rows padded to 72 f16 (144B = 4 banks mod 32 -> b128
// reads conflict-free). Producer-consumer wave split as R3: waves 0-3
// layer 1, waves 4-7 layer 2 one step behind, 1 barrier/iter.

#define B_TOT 8192
#define T_LEN 2048
#define MR    16
#define ROWW  72            // f16 per row: [h 0..50][x 51][1.0 52][0 ..63][pad]
#define HB    (MR*ROWW)     // 1152 f16 per parity buffer

typedef _Float16 f16x8 __attribute__((ext_vector_type(8)));
typedef float    f32x4 __attribute__((ext_vector_type(4)));

#define LOG2E 1.4426950408889634f

static __device__ __forceinline__ float us2f(unsigned short u) {
    unsigned int w = ((unsigned int)u) << 16;
    float f; __builtin_memcpy(&f, &w, 4);
    return f;
}
// load f32 from f32 or bf16 global
static __device__ __forceinline__ float ldf(const void* p, int idx, bool isbf) {
    return isbf ? us2f(((const unsigned short*)p)[idx])
                : ((const float*)p)[idx];
}
static __device__ __forceinline__ void store_y(void* outp, bool isbf, int idx, float v) {
    if (isbf) {
        unsigned int u; __builtin_memcpy(&u, &v, 4);
        u = (u + 0x7FFFu + ((u >> 16) & 1u)) >> 16;
        ((unsigned short*)outp)[idx] = (unsigned short)u;
    } else {
        ((float*)outp)[idx] = v;
    }
}

__global__ __launch_bounds__(512, 4)
void lstm2_kernel(const void* __restrict__ xin,
                  const void* __restrict__ Wih1, const void* __restrict__ Whh1,
                  const void* __restrict__ bih1, const void* __restrict__ bhh1,
                  const void* __restrict__ Wih2, const void* __restrict__ Whh2,
                  const void* __restrict__ bih2, const void* __restrict__ bhh2,
                  const void* __restrict__ Wlin, const void* __restrict__ blin,
                  void* __restrict__ outp)
{
    const int tid  = threadIdx.x;
    const int wset = tid >> 8;         // 0: layer-1 waves, 1: layer-2 waves
    const int wv   = (tid >> 6) & 3;   // j-slice within set
    const int ln   = tid & 63;
    const int lid  = ln & 15;
    const int quad = ln >> 4;
    const int b0   = blockIdx.x * MR;
    const int jcol = 13*wv + lid;
    const bool valid = (lid < 13) && (jcol < 51);
    const bool ylane = (wv == 3) && (lid == 12);   // pad col 51 -> y head

    __shared__ alignas(16) _Float16 hx [2*HB];   // h1 ping-pong + x/1.0 K-slots
    __shared__ alignas(16) _Float16 h2b[2*HB];   // h2 ping-pong

    // ---- dtype sniff (f32 vs bf16 globals), block-uniform ----
    bool isbf;
    {
        const unsigned short* xu = (const unsigned short*)xin;
        int cnt = 0;
        #pragma unroll
        for (int i = 0; i < 64; i += 2) {
            unsigned e = (xu[i] >> 7) & 0xFFu;
            cnt += (e >= 115u && e <= 131u) ? 1 : 0;
        }
        isbf = (cnt >= 16);
    }

    // ---- init LDS ----
    for (int i = tid; i < 2*HB; i += 512) {
        hx[i]  = (_Float16)0.0f;
        h2b[i] = (_Float16)0.0f;
    }
    __syncthreads();
    if (tid < MR) {
        hx[0*HB + tid*ROWW + 52] = (_Float16)1.0f;   // bias slot, both parities
        hx[1*HB + tid*ROWW + 52] = (_Float16)1.0f;
        hx[1*HB + tid*ROWW + 51] = (_Float16)ldf(xin, (b0 + tid)*T_LEN, isbf);
    }
    __syncthreads();

    if (wset == 0) {
        // ================= LAYER-1 WAVES =================
        // B-frag: k<51 -> sn*Whh1 ; k==51 -> sn*Wih1 (x slot) ; k==52 -> sn*bias
        f16x8 B1[4][2];
        #pragma unroll
        for (int n = 0; n < 4; ++n) {
            const int g = 51*n + jcol;
            const float sn = (n == 2) ? -2.0f*LOG2E : -LOG2E;
            #pragma unroll
            for (int kb = 0; kb < 2; ++kb) {
                f16x8 f;
                #pragma unroll
                for (int j8 = 0; j8 < 8; ++j8) {
                    const int k = kb*32 + quad*8 + j8;
                    float v = 0.0f;
                    if (valid) {
                        if (k < 51)       v = sn * ldf(Whh1, g*51 + k, isbf);
                        else if (k == 51) v = sn * ldf(Wih1, g, isbf);
                        else if (k == 52) v = sn * (ldf(bih1, g, isbf) + ldf(bhh1, g, isbf));
                    }
                    f[j8] = (_Float16)v;
                }
                B1[n][kb] = f;
            }
        }
        float c1[4] = {0,0,0,0};

        #pragma unroll 2
        for (int k = 0; k <= T_LEN; ++k) {
            if (k < T_LEN) {
                const int rs = (k - 1) & 1, ws = k & 1;
                // early x(k+1) prefetch (wave 0 lanes 0..15)
                const bool xl = (tid < MR) && (k + 1 < T_LEN);
                float xnext = 0.0f;
                if (xl) xnext = ldf(xin, (b0 + tid)*T_LEN + k + 1, isbf);

                const _Float16* hp = &hx[rs*HB + lid*ROWW + quad*8];
                const f16x8 a0 = *(const f16x8*)(hp);
                const f16x8 a1 = *(const f16x8*)(hp + 32);
                f32x4 acc[4];
                #pragma unroll
                for (int n = 0; n < 4; ++n) {
                    f32x4 z = {0.0f, 0.0f, 0.0f, 0.0f};
                    z      = __builtin_amdgcn_mfma_f32_16x16x32_f16(a0, B1[n][0], z, 0,0,0);
                    acc[n] = __builtin_amdgcn_mfma_f32_16x16x32_f16(a1, B1[n][1], z, 0,0,0);
                }
                // gates: d = 1 + 2^(scaled pre-act); paired rcp
                float s[4][4];
                #pragma unroll
                for (int n = 0; n < 4; ++n) {
                    float d0 = 1.0f + __builtin_amdgcn_exp2f(acc[n][0]);
                    float d1 = 1.0f + __builtin_amdgcn_exp2f(acc[n][1]);
                    float d2 = 1.0f + __builtin_amdgcn_exp2f(acc[n][2]);
                    float d3 = 1.0f + __builtin_amdgcn_exp2f(acc[n][3]);
                    const float Ra = __builtin_amdgcn_rcpf(d0*d1);
                    const float Rb = __builtin_amdgcn_rcpf(d2*d3);
                    if (n == 2) {   // tanh
                        s[n][0] = fmaf(2.0f, Ra*d1, -1.0f);
                        s[n][1] = fmaf(2.0f, Ra*d0, -1.0f);
                        s[n][2] = fmaf(2.0f, Rb*d3, -1.0f);
                        s[n][3] = fmaf(2.0f, Rb*d2, -1.0f);
                    } else {        // sigmoid
                        s[n][0] = Ra*d1; s[n][1] = Ra*d0;
                        s[n][2] = Rb*d3; s[n][3] = Rb*d2;
                    }
                }
                // cell update + tanh(c) (paired, clamped) + h store
                float dd[4];
                #pragma unroll
                for (int r = 0; r < 4; ++r) {
                    const float c = fmaf(s[1][r], c1[r], s[0][r]*s[2][r]);
                    c1[r] = c;
                    float a = -2.0f*LOG2E*c;
                    a = fminf(fmaxf(a, -80.0f), 80.0f);
                    dd[r] = 1.0f + __builtin_amdgcn_exp2f(a);
                }
                const float Rc = __builtin_amdgcn_rcpf(dd[0]*dd[1]);
                const float Rd = __builtin_amdgcn_rcpf(dd[2]*dd[3]);
                float h[4];
                h[0] = s[3][0] * fmaf(2.0f, Rc*dd[1], -1.0f);
                h[1] = s[3][1] * fmaf(2.0f, Rc*dd[0], -1.0f);
                h[2] = s[3][2] * fmaf(2.0f, Rd*dd[3], -1.0f);
                h[3] = s[3][3] * fmaf(2.0f, Rd*dd[2], -1.0f);
                if (valid) {
                    #pragma unroll
                    for (int r = 0; r < 4; ++r)
                        hx[ws*HB + (quad*4 + r)*ROWW + jcol] = (_Float16)h[r];
                }
                if (xl) hx[ws*HB + tid*ROWW + 51] = (_Float16)xnext;
            }
            __syncthreads();
        }
    } else {
        // ================= LAYER-2 WAVES =================
        // B2i over h1-path A (k<51: Wih2; k==51: 0 kills x slot; k==52: bias
        // [or blin on y pad col]); B2h over h2-path A (k<51: Whh2 [or Wlin]).
        f16x8 B2i[4][2], B2h[4][2];
        #pragma unroll
        for (int n = 0; n < 4; ++n) {
            const int g = 51*n + jcol;
            const float sn = (n == 2) ? -2.0f*LOG2E : -LOG2E;
            #pragma unroll
            for (int kb = 0; kb < 2; ++kb) {
                f16x8 fi, fh;
                #pragma unroll
                for (int j8 = 0; j8 < 8; ++j8) {
                    const int k = kb*32 + quad*8 + j8;
                    float vi = 0.0f, vh = 0.0f;
                    if (valid) {
                        if (k < 51) {
                            vi = sn * ldf(Wih2, g*51 + k, isbf);
                            vh = sn * ldf(Whh2, g*51 + k, isbf);
                        } else if (k == 52) {
                            vi = sn * (ldf(bih2, g, isbf) + ldf(bhh2, g, isbf));
                        }
                    } else if (ylane && n == 3) {
                        if (k < 51)       vh = ldf(Wlin, k, isbf);
                        else if (k == 52) vi = ldf(blin, 0, isbf);
                    }
                    fi[j8] = (_Float16)vi; fh[j8] = (_Float16)vh;
                }
                B2i[n][kb] = fi; B2h[n][kb] = fh;
            }
        }
        const float bl = ldf(blin, 0, isbf);
        float c2[4] = {0,0,0,0};

        #pragma unroll 2
        for (int k = 0; k <= T_LEN; ++k) {
            if (k >= 1) {
                const int rs1 = (k - 1) & 1;   // h1(k-1) + x/bias slots
                const int rs2 = k & 1;         // h2(k-2)
                const int ws2 = (k - 1) & 1;   // h2(k-1)
                const _Float16* h1p = &hx [rs1*HB + lid*ROWW + quad*8];
                const _Float16* h2p = &h2b[rs2*HB + lid*ROWW + quad*8];
                const f16x8 p0 = *(const f16x8*)(h1p);
                const f16x8 p1 = *(const f16x8*)(h1p + 32);
                const f16x8 q0 = *(const f16x8*)(h2p);
                const f16x8 q1 = *(const f16x8*)(h2p + 32);
                f32x4 acc[4];
                #pragma unroll
                for (int n = 0; n < 4; ++n) {
                    f32x4 z = {0.0f, 0.0f, 0.0f, 0.0f};
                    z      = __builtin_amdgcn_mfma_f32_16x16x32_f16(p0, B2i[n][0], z, 0,0,0);
                    z      = __builtin_amdgcn_mfma_f32_16x16x32_f16(p1, B2i[n][1], z, 0,0,0);
                    z      = __builtin_amdgcn_mfma_f32_16x16x32_f16(q0, B2h[n][0], z, 0,0,0);
                    acc[n] = __builtin_amdgcn_mfma_f32_16x16x32_f16(q1, B2h[n][1], z, 0,0,0);
                }
                if (ylane && k >= 2) {   // pad col: blin + Wlin.h2(k-2) = y[k-2]
                    #pragma unroll
                    for (int r = 0; r < 4; ++r)
                        store_y(outp, isbf, (b0 + quad*4 + r)*T_LEN + (k - 2), acc[3][r]);
                }
                float s[4][4];
                #pragma unroll
                for (int n = 0; n < 4; ++n) {
                    float d0 = 1.0f + __builtin_amdgcn_exp2f(acc[n][0]);
                    float d1 = 1.0f + __builtin_amdgcn_exp2f(acc[n][1]);
                    float d2 = 1.0f + __builtin_amdgcn_exp2f(acc[n][2]);
                    float d3 = 1.0f + __builtin_amdgcn_exp2f(acc[n][3]);
                    const float Ra = __builtin_amdgcn_rcpf(d0*d1);
                    const float Rb = __builtin_amdgcn_rcpf(d2*d3);
                    if (n == 2) {
                        s[n][0] = fmaf(2.0f, Ra*d1, -1.0f);
                        s[n][1] = fmaf(2.0f, Ra*d0, -1.0f);
                        s[n][2] = fmaf(2.0f, Rb*d3, -1.0f);
                        s[n][3] = fmaf(2.0f, Rb*d2, -1.0f);
                    } else {
                        s[n][0] = Ra*d1; s[n][1] = Ra*d0;
                        s[n][2] = Rb*d3; s[n][3] = Rb*d2;
                    }
                }
                float dd[4];
                #pragma unroll
                for (int r = 0; r < 4; ++r) {
                    const float c = fmaf(s[1][r], c2[r], s[0][r]*s[2][r]);
                    c2[r] = c;
                    float a = -2.0f*LOG2E*c;
                    a = fminf(fmaxf(a, -80.0f), 80.0f);
                    dd[r] = 1.0f + __builtin_amdgcn_exp2f(a);
                }
                const float Rc = __builtin_amdgcn_rcpf(dd[0]*dd[1]);
                const float Rd = __builtin_amdgcn_rcpf(dd[2]*dd[3]);
                float h[4];
                h[0] = s[3][0] * fmaf(2.0f, Rc*dd[1], -1.0f);
                h[1] = s[3][1] * fmaf(2.0f, Rc*dd[0], -1.0f);
                h[2] = s[3][2] * fmaf(2.0f, Rd*dd[3], -1.0f);
                h[3] = s[3][3] * fmaf(2.0f, Rd*dd[2], -1.0f);
                if (valid) {
                    #pragma unroll
                    for (int r = 0; r < 4; ++r)
                        h2b[ws2*HB + (quad*4 + r)*ROWW + jcol] = (_Float16)h[r];
                }
            }
            __syncthreads();
        }

        // ---- flush y[T-1] from final h2 (parity (T-1)&1) ----
        if (wv == 3) {
            const _Float16* h2p = &h2b[((T_LEN - 1) & 1)*HB + lid*ROWW + quad*8];
            const f16x8 q0 = *(const f16x8*)(h2p);
            const f16x8 q1 = *(const f16x8*)(h2p + 32);
            f32x4 z = {bl, bl, bl, bl};
            z = __builtin_amdgcn_mfma_f32_16x16x32_f16(q0, B2h[3][0], z, 0,0,0);
            z = __builtin_amdgcn_mfma_f32_16x16x32_f16(q1, B2h[3][1], z, 0,0,0);
            if (lid == 12) {
                #pragma unroll
                for (int r = 0; r < 4; ++r)
                    store_y(outp, isbf, (b0 + quad*4 + r)*T_LEN + (T_LEN - 1), z[r]);
            }
        }
    }
}

extern "C" void kernel_launch(void* const* d_in, const int* in_sizes, int n_in,
                              void* d_out, int out_size, void* d_ws, size_t ws_size,
                              hipStream_t stream) {
    (void)in_sizes; (void)n_in; (void)out_size; (void)d_ws; (void)ws_size;
    dim3 grid(B_TOT / MR), block(512);
    lstm2_kernel<<<grid, block, 0, stream>>>(
        d_in[0], d_in[1], d_in[2], d_in[3], d_in[4], d_in[5],
        d_in[6], d_in[7], d_in[8], d_in[9], d_in[10], d_out);
}